// Round 3
// baseline (562.247 us; speedup 1.0000x reference)
//
#include <hip/hip_runtime.h>

// score[i] = dot(x[src[i]], W1) + dot(x[dst[i]], W2) + dot(e[i], W3) + b
// Factored: per-node s[n]=x[n].W1, t[n]=x[n].W2 (x read ONCE, 102 MB),
// then per-edge two scalar gathers (L2-resident 400 KB table) + one
// coalesced e-row dot (328 MB). Compulsory traffic ~432 MB -> ~66 us floor.
//
// R3: persistent edge waves (8192 = 256 CU x 32) grid-striding over 4-edge
// groups with a 2-deep software pipeline: group g+stride's row loads and
// index gathers are issued BEFORE reducing group g, so ~8 KB/wave stays in
// flight through the shuffle-reduce chain. W3 regs amortize over ~5 groups.

constexpr int D = 512;

__device__ __forceinline__ float dot4(const float4 a, const float4 b) {
    return a.x * b.x + a.y * b.y + a.z * b.z + a.w * b.w;
}

// Reduce TWO per-lane values across the 64-lane wave in 7 shuffles.
// Lanes 0-31 end holding sum(u), lanes 32-63 sum(v).
__device__ __forceinline__ float reduce_pair(float u, float v, int lane) {
    u += __shfl_xor(u, 32, 64);
    v += __shfl_xor(v, 32, 64);
    float z = (lane < 32) ? u : v;
#pragma unroll
    for (int off = 16; off > 0; off >>= 1) z += __shfl_xor(z, off, 64);
    return z;
}

// One wave per 4 nodes, exact cover. Lane l covers float4s {l, 64+l} of each
// 512-wide row -> every load is a fully coalesced contiguous 1 KB wave access.
__global__ __launch_bounds__(256) void node_scores_kernel(
    const float* __restrict__ x, const float* __restrict__ W,
    float* __restrict__ s_out, float* __restrict__ t_out, int n_nodes)
{
    const int lane = threadIdx.x & 63;
    const int wave = (blockIdx.x * blockDim.x + threadIdx.x) >> 6;

    const float4* W4 = (const float4*)W;
    const float4 w1a = W4[lane],       w1b = W4[64 + lane];
    const float4 w2a = W4[128 + lane], w2b = W4[192 + lane];

    const int n0 = wave * 4;
    if (n0 >= n_nodes) return;

    float4 xa[4], xb[4];
#pragma unroll
    for (int r = 0; r < 4; ++r) {
        int n = n0 + r;
        if (n >= n_nodes) n = n_nodes - 1;   // wave-uniform clamp
        const float4* xr = (const float4*)(x + (size_t)n * D);
        xa[r] = xr[lane];
        xb[r] = xr[64 + lane];
    }
#pragma unroll
    for (int r = 0; r < 4; ++r) {
        const float s = dot4(xa[r], w1a) + dot4(xb[r], w1b);
        const float t = dot4(xa[r], w2a) + dot4(xb[r], w2b);
        const float z = reduce_pair(s, t, lane);
        const int n = n0 + r;
        if (n < n_nodes) {
            if (lane == 0)  s_out[n] = z;
            if (lane == 32) t_out[n] = z;
        }
    }
}

// Persistent waves, grid-stride over groups of 4 edges, 2-deep pipeline.
__global__ __launch_bounds__(256) void edge_scores_kernel(
    const float* __restrict__ e, const int* __restrict__ src,
    const int* __restrict__ dst, const float* __restrict__ W,
    const float* __restrict__ bp, const float* __restrict__ s_in,
    const float* __restrict__ t_in, float* __restrict__ out, int n_edges)
{
    const int lane    = threadIdx.x & 63;
    const int wave    = (blockIdx.x * blockDim.x + threadIdx.x) >> 6;
    const int n_waves = (gridDim.x * blockDim.x) >> 6;

    const float4* W4 = (const float4*)W;
    const float4 w3a = W4[256 + lane], w3b = W4[320 + lane];
    const float bias = bp[0];

    const int n_groups = n_edges >> 2;   // 160000 % 4 == 0

    float4 ea[2][4], eb[2][4];
    float  sv[2][4];

#define LOAD_GROUP(g, buf)                                              \
    {                                                                   \
        const int base_ = (g) * 4;                                      \
        _Pragma("unroll")                                               \
        for (int r_ = 0; r_ < 4; ++r_) {                                \
            const int i_ = base_ + r_;                                  \
            const float4* er_ = (const float4*)(e + (size_t)i_ * D);    \
            ea[buf][r_] = er_[lane];                                    \
            eb[buf][r_] = er_[64 + lane];                               \
            sv[buf][r_] = s_in[src[i_]] + t_in[dst[i_]] + bias;         \
        }                                                               \
    }

    int g = wave;
    if (g >= n_groups) return;

    LOAD_GROUP(g, 0)
    int buf = 0;
    for (; g < n_groups; g += n_waves) {
        const int gn = g + n_waves;
        if (gn < n_groups) LOAD_GROUP(gn, buf ^ 1)   // prefetch next group

#pragma unroll
        for (int r = 0; r < 4; r += 2) {
            const float p0 = dot4(ea[buf][r],     w3a) + dot4(eb[buf][r],     w3b);
            const float p1 = dot4(ea[buf][r + 1], w3a) + dot4(eb[buf][r + 1], w3b);
            const float z  = reduce_pair(p0, p1, lane);
            const int base = g * 4;
            if (lane == 0)  out[base + r]     = z + sv[buf][r];
            if (lane == 32) out[base + r + 1] = z + sv[buf][r + 1];
        }
        buf ^= 1;
    }
#undef LOAD_GROUP
}

extern "C" void kernel_launch(void* const* d_in, const int* in_sizes, int n_in,
                              void* d_out, int out_size, void* d_ws, size_t ws_size,
                              hipStream_t stream) {
    const float* x   = (const float*)d_in[0];
    const float* e   = (const float*)d_in[1];
    const int*   src = (const int*)d_in[2];
    const int*   dst = (const int*)d_in[3];
    const float* W   = (const float*)d_in[4];
    const float* b   = (const float*)d_in[5];

    const int n_nodes = in_sizes[0] / D;   // 50000
    const int n_edges = in_sizes[2];       // 160000

    float* s   = (float*)d_ws;             // [n_nodes]
    float* t   = s + n_nodes;              // [n_nodes]
    float* out = (float*)d_out;            // [n_edges]

    // Node: exact cover, 4 nodes/wave -> ceil(50000/16) blocks.
    const int node_blocks = (n_nodes + 15) / 16;
    node_scores_kernel<<<node_blocks, 256, 0, stream>>>(x, W, s, t, n_nodes);

    // Edge: persistent 2048 blocks = 8192 waves (32 waves/CU), ~4.9 groups/wave.
    edge_scores_kernel<<<2048, 256, 0, stream>>>(e, src, dst, W, b, s, t, out, n_edges);
}

// Round 4
// 487.497 us; speedup vs baseline: 1.1533x; 1.1533x over previous
//
#include <hip/hip_runtime.h>

// score[i] = dot(x[src[i]], W1) + dot(x[dst[i]], W2) + dot(e[i], W3) + b
// Factored: precompute per-node s[n]=x[n].W1, t[n]=x[n].W2 (reads x ONCE),
// then per-edge gather of two scalars + one coalesced e-row dot.
//
// R4 = revert to R1 (measured-fastest, 482.9 us). R2's ILP/shuffle-halving
// restructure was neutral (487.3) and R3's persistent pipeline regressed
// (562, VGPR-pressure + scattered stride) -> both kernels are at the
// compulsory-traffic floor (~432 MB -> ~69 us @ 6.3 TB/s); the rest of the
// timed window is harness ws-poison (1.31 GB ~200 us) + input restore.

constexpr int D = 512;

__device__ __forceinline__ float dot4(const float4 a, const float4 b) {
    return a.x * b.x + a.y * b.y + a.z * b.z + a.w * b.w;
}

// One wave (64 lanes) per node. Lane l covers float4s {l, 64+l} of the
// 512-wide row -> each load instruction is a fully coalesced contiguous
// 1 KB wave access.
__global__ __launch_bounds__(256) void node_scores_kernel(
    const float* __restrict__ x, const float* __restrict__ W,
    float* __restrict__ s_out, float* __restrict__ t_out, int n_nodes)
{
    const int lane    = threadIdx.x & 63;
    const int wave    = (blockIdx.x * blockDim.x + threadIdx.x) >> 6;
    const int n_waves = (gridDim.x * blockDim.x) >> 6;

    const float4* W4 = (const float4*)W;
    // W1 = W[0:512), W2 = W[512:1024) — held in registers across the loop.
    const float4 w1a = W4[lane];
    const float4 w1b = W4[64 + lane];
    const float4 w2a = W4[128 + lane];
    const float4 w2b = W4[192 + lane];

    for (int n = wave; n < n_nodes; n += n_waves) {
        const float4* xr = (const float4*)(x + (size_t)n * D);
        const float4 xa = xr[lane];
        const float4 xb = xr[64 + lane];
        float s = dot4(xa, w1a) + dot4(xb, w1b);
        float t = dot4(xa, w2a) + dot4(xb, w2b);
#pragma unroll
        for (int off = 32; off > 0; off >>= 1) {
            s += __shfl_xor(s, off, 64);
            t += __shfl_xor(t, off, 64);
        }
        if (lane == 0) {
            s_out[n] = s;
            t_out[n] = t;
        }
    }
}

// One wave per edge. W3 fragment lives in registers for ~20 edges/wave.
// Index + node-score gathers are wave-uniform broadcasts (single cache line)
// issued BEFORE the row dot so their latency hides under the 2 KB row fetch.
__global__ __launch_bounds__(256) void edge_scores_kernel(
    const float* __restrict__ e, const int* __restrict__ src,
    const int* __restrict__ dst, const float* __restrict__ W,
    const float* __restrict__ bp, const float* __restrict__ s_in,
    const float* __restrict__ t_in, float* __restrict__ out, int n_edges)
{
    const int lane    = threadIdx.x & 63;
    const int wave    = (blockIdx.x * blockDim.x + threadIdx.x) >> 6;
    const int n_waves = (gridDim.x * blockDim.x) >> 6;

    const float4* W4 = (const float4*)W;
    // W3 = W[1024:1536)
    const float4 w3a = W4[256 + lane];
    const float4 w3b = W4[320 + lane];
    const float bias = bp[0];

    for (int i = wave; i < n_edges; i += n_waves) {
        const int   si = src[i];
        const int   di = dst[i];
        const float sv = s_in[si];
        const float tv = t_in[di];

        const float4* er = (const float4*)(e + (size_t)i * D);
        const float4 ea = er[lane];
        const float4 eb = er[64 + lane];
        float p = dot4(ea, w3a) + dot4(eb, w3b);
#pragma unroll
        for (int off = 32; off > 0; off >>= 1) p += __shfl_xor(p, off, 64);

        if (lane == 0) out[i] = p + sv + tv + bias;
    }
}

extern "C" void kernel_launch(void* const* d_in, const int* in_sizes, int n_in,
                              void* d_out, int out_size, void* d_ws, size_t ws_size,
                              hipStream_t stream) {
    const float* x   = (const float*)d_in[0];
    const float* e   = (const float*)d_in[1];
    const int*   src = (const int*)d_in[2];
    const int*   dst = (const int*)d_in[3];
    const float* W   = (const float*)d_in[4];
    const float* b   = (const float*)d_in[5];

    const int n_nodes = in_sizes[0] / D;   // 50000
    const int n_edges = in_sizes[2];       // 160000

    float* s   = (float*)d_ws;             // [n_nodes]
    float* t   = s + n_nodes;              // [n_nodes]
    float* out = (float*)d_out;            // [n_edges]

    // 1024 blocks * 4 waves = 4096 waves over 50000 nodes (~12 nodes/wave).
    node_scores_kernel<<<1024, 256, 0, stream>>>(x, W, s, t, n_nodes);
    // 2048 blocks * 4 waves = 8192 waves over 160000 edges (~20 edges/wave).
    edge_scores_kernel<<<2048, 256, 0, stream>>>(e, src, dst, W, b, s, t, out, n_edges);
}